// Round 6
// baseline (373.012 us; speedup 1.0000x reference)
//
#include <hip/hip_runtime.h>
#include <hip/hip_bf16.h>
#include <stdint.h>

// B=16, T=512, D=512, H=8, DH=64, TE=2048, B2=32. M = 16384 rows.

typedef float f32x4 __attribute__((ext_vector_type(4)));
typedef short s16x8 __attribute__((ext_vector_type(8)));   // 8 bf16 in 4 VGPRs

#define MFMA16(a, b, c) __builtin_amdgcn_mfma_f32_16x16x32_bf16((a), (b), (c), 0, 0, 0)
// async global->LDS, 16B/lane; LDS dest = wave-uniform base + lane*16
#define GLD16(g, l) __builtin_amdgcn_global_load_lds( \
    (const __attribute__((address_space(1))) void*)(g), \
    (__attribute__((address_space(3))) void*)(l), 16, 0, 0)

__device__ __forceinline__ ushort f2bf(float f) {
    union { float f; uint32_t u; } cv; cv.f = f;
    uint32_t u = cv.u;
    return (ushort)((u + 0x7fffu + ((u >> 16) & 1u)) >> 16);
}
__device__ __forceinline__ float bf2f(ushort u) {
    union { uint32_t u; float f; } cv; cv.u = ((uint32_t)u) << 16;
    return cv.f;
}
// pack two fp32 -> two bf16 (round-to-nearest, carry-correct), 5 VALU ops
__device__ __forceinline__ uint32_t pack_bf2(float a, float b) {
    union { float f; uint32_t u; } x, y; x.f = a; y.f = b;
    return ((x.u + 0x8000u) >> 16) | ((y.u + 0x8000u) & 0xffff0000u);
}
__device__ __forceinline__ float fast_exp2(float x) {
#if __has_builtin(__builtin_amdgcn_exp2f)
    return __builtin_amdgcn_exp2f(x);
#else
    return exp2f(x);
#endif
}
__device__ __forceinline__ float wave_sum(float v) {
#pragma unroll
    for (int o = 32; o > 0; o >>= 1) v += __shfl_xor(v, o);
    return v;
}

#define QSCALE 0.180336880f   // 0.125 * log2(e): folded into q so p = exp2(S)
#define MNEG  -144269.504f    // -1e5 * log2(e): mask penalty in exp2 domain

// ---------------------------------------------------------------------------
// Fused prep kernel — independent work packed into one launch (256-thr blocks):
//  [0,1024)      wconv: Wt[n][k] = bf16(W[k][n]) for Wq/Wk/Wv/Wout
//  [1024,5120)   ln_prep: dual LayerNorm -> xn, tn (4 rows/block)
//  [5120,7168)   maskchk: flags[tile] = any(mask != 1) per 64x64 tile
//  [7168,7296)   ss init: ss[b][n] = bemb[n]
// ---------------------------------------------------------------------------
__global__ __launch_bounds__(256) void prep(
    const float* __restrict__ w0, const float* __restrict__ w1,
    const float* __restrict__ w2, const float* __restrict__ w3,
    ushort* __restrict__ o0, ushort* __restrict__ o1,
    ushort* __restrict__ o2, ushort* __restrict__ o3,
    const float* __restrict__ x1, const float* __restrict__ x2,
    const float* __restrict__ gx, const float* __restrict__ bx,
    const float* __restrict__ gt, const float* __restrict__ bt,
    ushort* __restrict__ xn, ushort* __restrict__ tn,
    const float* __restrict__ mask, int* __restrict__ flags,
    const float* __restrict__ bemb, float* __restrict__ ss) {
    __shared__ float tile[32][33];
    __shared__ int bad4[4];
    const int bid = blockIdx.x, tid = threadIdx.x;

    if (bid < 1024) {
        // ---- weight transpose + cast (32x32 tiles) ----
        const int z = bid >> 8, xy = bid & 255;
        const float* src; ushort* dst;
        switch (z) {
            case 0: src = w0; dst = o0; break;
            case 1: src = w1; dst = o1; break;
            case 2: src = w2; dst = o2; break;
            default: src = w3; dst = o3; break;
        }
        const int n0 = (xy & 15) * 32, k0 = (xy >> 4) * 32;
        const int x = tid & 31, y0 = tid >> 5;
#pragma unroll
        for (int i = 0; i < 4; i++) {
            int yy = y0 + 8 * i;
            tile[yy][x] = src[(size_t)(k0 + yy) * 512 + n0 + x];
        }
        __syncthreads();
#pragma unroll
        for (int i = 0; i < 4; i++) {
            int yy = y0 + 8 * i;
            dst[(size_t)(n0 + yy) * 512 + k0 + x] = f2bf(tile[x][yy]);
        }
    } else if (bid < 5120) {
        // ---- dual LayerNorm, stats once per source row ----
        const int r = (bid - 1024) * 4 + (tid >> 6);
        const int lane = tid & 63;
        const float* src = (r < 8192) ? x1 + (size_t)r * 512
                                      : x2 + (size_t)(r - 8192) * 512;
        const int tr = (r < 8192) ? r + 8192 : r - 8192;
        const int d0 = lane * 4;
        float4 a0 = *(const float4*)&src[d0];
        float4 a1 = *(const float4*)&src[d0 + 256];
        float s = a0.x + a0.y + a0.z + a0.w + a1.x + a1.y + a1.z + a1.w;
        float q = a0.x*a0.x + a0.y*a0.y + a0.z*a0.z + a0.w*a0.w
                + a1.x*a1.x + a1.y*a1.y + a1.z*a1.z + a1.w*a1.w;
        s = wave_sum(s); q = wave_sum(q);
        const float mean = s * (1.f/512.f);
        const float var = q * (1.f/512.f) - mean * mean;
        const float rs = rsqrtf(var + 1e-5f);
        float vals[8] = {a0.x, a0.y, a0.z, a0.w, a1.x, a1.y, a1.z, a1.w};
        ushort* px = xn + (size_t)r * 512;
        ushort* pt = tn + (size_t)tr * 512;
#pragma unroll
        for (int half = 0; half < 2; half++) {
            ushort4 ox, ot;
            ushort* pox = (ushort*)&ox; ushort* pot = (ushort*)&ot;
#pragma unroll
            for (int j = 0; j < 4; j++) {
                int d = d0 + half * 256 + j;
                float nv = (vals[half * 4 + j] - mean) * rs;
                pox[j] = f2bf(nv * gx[d] + bx[d]);
                pot[j] = f2bf(nv * gt[d] + bt[d]);
            }
            *(ushort4*)&px[d0 + half * 256] = ox;
            *(ushort4*)&pt[d0 + half * 256] = ot;
        }
    } else if (bid < 7168) {
        // ---- mask precheck: one block per 64x64 tile, mask read once ----
        const int b = bid - 5120;             // 0..2047
        const int b2 = b >> 6, qt = (b >> 3) & 7, kt = b & 7;
        const int r = tid >> 2, c4 = tid & 3;
        const float* mrow = mask + ((size_t)(b2 * 512 + qt * 64 + r)) * 512 + kt * 64;
        bool bad = false;
#pragma unroll
        for (int j = 0; j < 4; j++) {
            float4 v = *(const float4*)&mrow[(c4 + 4 * j) * 4];
            bad |= (v.x != 1.f) | (v.y != 1.f) | (v.z != 1.f) | (v.w != 1.f);
        }
        unsigned long long bl = __ballot(bad);
        const int w = tid >> 6;
        if ((tid & 63) == 0) bad4[w] = (bl != 0ull);
        __syncthreads();
        if (tid == 0) flags[b] = bad4[0] | bad4[1] | bad4[2] | bad4[3];
    } else {
        // ---- ss init with bias ----
        int i = (bid - 7168) * 256 + tid;     // 32768 total
        ss[i] = bemb[i & 1023];
    }
}

// ---------------------------------------------------------------------------
// emb path: ss[b][0:1024] += silu(emb[b]) @ Wemb  (k-split, fp32 atomics)
// ---------------------------------------------------------------------------
__global__ __launch_bounds__(256) void emb_gemm(const float* __restrict__ emb,
                                                const float* __restrict__ Wemb,
                                                float* __restrict__ ss) {
    __shared__ float es[32 * 128];
    const int n0 = blockIdx.x * 128, k0 = blockIdx.y * 128;
    const int t = threadIdx.x;
#pragma unroll
    for (int i = 0; i < 16; i++) {
        int idx = t + 256 * i;
        int b = idx >> 7, kk = idx & 127;
        float v = emb[(size_t)b * 2048 + k0 + kk];
        es[idx] = v / (1.f + __expf(-v));
    }
    __syncthreads();
    const int n = n0 + (t & 127);
    const int kh = (t >> 7) * 64;
    float acc[32];
#pragma unroll
    for (int b = 0; b < 32; b++) acc[b] = 0.f;
    for (int kk = kh; kk < kh + 64; kk++) {
        float w = Wemb[(size_t)(k0 + kk) * 1024 + n];
#pragma unroll
        for (int b = 0; b < 32; b++) acc[b] += es[b * 128 + kk] * w;
    }
#pragma unroll
    for (int b = 0; b < 32; b++) atomicAdd(&ss[b * 1024 + n], acc[b]);
}

// ---------------------------------------------------------------------------
// Fused QKV GEMM: [16384 x 1536] = {xn|tn}[M x 512] @ Wqkv[1536 x 512]^T.
// m97 regime: single-buffer 32 KB LDS, 2-barrier K-loop, GLD16 + XOR swizzle.
// ---------------------------------------------------------------------------
__global__ __launch_bounds__(256, 3) void gemm_qkv(
    const ushort* __restrict__ xn, const ushort* __restrict__ tn,
    const ushort* __restrict__ W,
    const float* __restrict__ bq, const float* __restrict__ bk,
    const float* __restrict__ bv,
    ushort* __restrict__ qb, ushort* __restrict__ kb,
    ushort* __restrict__ vtb) {
    __shared__ ushort As[128 * 64];
    __shared__ ushort Bs[128 * 64];
    const int tid = threadIdx.x;
    const int lane = tid & 63, w = tid >> 6;
    const int l15 = lane & 15, quad = lane >> 4;
    const int l8 = lane >> 3, c_src = (lane & 7) ^ l8;
    const int bid = blockIdx.x;
    const int xcd = bid & 7, j = bid >> 3;        // j in [0,192)
    const int mt_l = j / 12, nt = j % 12;
    const int m0 = (xcd * 16 + mt_l) * 128, n0 = nt * 128;
    const ushort* A = (n0 < 512) ? xn : tn;
    const int wm = (w >> 1) * 64, wn = (w & 1) * 64;

    f32x4 zero = {0.f, 0.f, 0.f, 0.f};
    f32x4 acc[4][4];
#pragma unroll
    for (int i = 0; i < 4; i++)
#pragma unroll
        for (int jj = 0; jj < 4; jj++) acc[i][jj] = zero;

    const ushort* ga0 = A + (size_t)(m0 + w * 32 + l8) * 512 + c_src * 8;
    const ushort* gb0 = W + (size_t)(n0 + w * 32 + l8) * 512 + c_src * 8;

    for (int k0 = 0; k0 < 512; k0 += 64) {
#pragma unroll
        for (int i = 0; i < 4; i++) {
            GLD16(ga0 + (size_t)(i * 8) * 512 + k0, &As[(w * 32 + i * 8) * 64]);
            GLD16(gb0 + (size_t)(i * 8) * 512 + k0, &Bs[(w * 32 + i * 8) * 64]);
        }
        __syncthreads();
#pragma unroll
        for (int ks = 0; ks < 2; ks++) {
            const int sl = ((ks * 4 + quad) ^ (l15 & 7)) * 8;
            s16x8 af[4], bf[4];
#pragma unroll
            for (int i = 0; i < 4; i++)
                af[i] = *(const s16x8*)&As[(wm + i * 16 + l15) * 64 + sl];
#pragma unroll
            for (int jj = 0; jj < 4; jj++)
                bf[jj] = *(const s16x8*)&Bs[(wn + jj * 16 + l15) * 64 + sl];
#pragma unroll
            for (int i = 0; i < 4; i++)
#pragma unroll
                for (int jj = 0; jj < 4; jj++)
                    acc[i][jj] = MFMA16(af[i], bf[jj], acc[i][jj]);
        }
        __syncthreads();
    }

#pragma unroll
    for (int i = 0; i < 4; i++)
#pragma unroll
        for (int jj = 0; jj < 4; jj++) {
            const int col = n0 + wn + jj * 16 + l15;
            if (n0 < 512) {          // q: bf16, scaled
                const float bvv = bq[col];
#pragma unroll
                for (int reg = 0; reg < 4; reg++) {
                    const int row = m0 + wm + i * 16 + quad * 4 + reg;
                    qb[(size_t)row * 512 + col] = f2bf((acc[i][jj][reg] + bvv) * QSCALE);
                }
            } else if (n0 < 1024) {  // k: bf16 row-major
                const int ck = col - 512;
                const float bvv = bk[ck];
#pragma unroll
                for (int reg = 0; reg < 4; reg++) {
                    const int row = m0 + wm + i * 16 + quad * 4 + reg;
                    kb[(size_t)row * 512 + ck] = f2bf(acc[i][jj][reg] + bvv);
                }
            } else {                 // v: transposed vt[b,h,dh,t]
                const int c2 = col - 1024;
                const float bvv = bv[c2];
                const int b2 = m0 >> 9;
                const int t0 = (m0 & 511) + wm + i * 16 + quad * 4;
                ushort4 o4; ushort* po = (ushort*)&o4;
#pragma unroll
                for (int reg = 0; reg < 4; reg++)
                    po[reg] = f2bf(acc[i][jj][reg] + bvv);
                *(ushort4*)&vtb[((size_t)((b2 * 8 + (c2 >> 6)) * 64 + (c2 & 63))) * 512 + t0] = o4;
            }
        }
}

// ---------------------------------------------------------------------------
// Output GEMM + bias + residual (fp32 out), same m97 regime.
// ---------------------------------------------------------------------------
__global__ __launch_bounds__(256, 3) void gemm_out(
    const ushort* __restrict__ A, const ushort* __restrict__ Bt,
    const float* __restrict__ bias, float* __restrict__ of,
    const float* __restrict__ r1, const float* __restrict__ r2) {
    __shared__ ushort As[128 * 64];
    __shared__ ushort Bs[128 * 64];
    const int tid = threadIdx.x;
    const int lane = tid & 63, w = tid >> 6;
    const int l15 = lane & 15, quad = lane >> 4;
    const int l8 = lane >> 3, c_src = (lane & 7) ^ l8;
    const int bid = blockIdx.x;
    const int xcd = bid & 7, j2 = bid >> 3;       // j2 in [0,64)
    const int m0 = (xcd * 16 + (j2 >> 2)) * 128;
    const int n0 = (j2 & 3) * 128;
    const int wm = (w >> 1) * 64, wn = (w & 1) * 64;

    f32x4 zero = {0.f, 0.f, 0.f, 0.f};
    f32x4 acc[4][4];
#pragma unroll
    for (int i = 0; i < 4; i++)
#pragma unroll
        for (int jj = 0; jj < 4; jj++) acc[i][jj] = zero;

    const ushort* ga0 = A + (size_t)(m0 + w * 32 + l8) * 512 + c_src * 8;
    const ushort* gb0 = Bt + (size_t)(n0 + w * 32 + l8) * 512 + c_src * 8;

    for (int k0 = 0; k0 < 512; k0 += 64) {
#pragma unroll
        for (int i = 0; i < 4; i++) {
            GLD16(ga0 + (size_t)(i * 8) * 512 + k0, &As[(w * 32 + i * 8) * 64]);
            GLD16(gb0 + (size_t)(i * 8) * 512 + k0, &Bs[(w * 32 + i * 8) * 64]);
        }
        __syncthreads();
#pragma unroll
        for (int ks = 0; ks < 2; ks++) {
            const int sl = ((ks * 4 + quad) ^ (l15 & 7)) * 8;
            s16x8 af[4], bf[4];
#pragma unroll
            for (int i = 0; i < 4; i++)
                af[i] = *(const s16x8*)&As[(wm + i * 16 + l15) * 64 + sl];
#pragma unroll
            for (int jj = 0; jj < 4; jj++)
                bf[jj] = *(const s16x8*)&Bs[(wn + jj * 16 + l15) * 64 + sl];
#pragma unroll
            for (int i = 0; i < 4; i++)
#pragma unroll
                for (int jj = 0; jj < 4; jj++)
                    acc[i][jj] = MFMA16(af[i], bf[jj], acc[i][jj]);
        }
        __syncthreads();
    }

#pragma unroll
    for (int i = 0; i < 4; i++)
#pragma unroll
        for (int jj = 0; jj < 4; jj++) {
            const int col = n0 + wn + jj * 16 + l15;
            const float bvv = bias[col];
#pragma unroll
            for (int reg = 0; reg < 4; reg++) {
                const int row = m0 + wm + i * 16 + quad * 4 + reg;
                float res = (row < 8192)
                                ? r1[(size_t)row * 512 + col]
                                : r2[(size_t)(row - 8192) * 512 + col];
                of[(size_t)row * 512 + col] = acc[i][jj][reg] + bvv + res;
            }
        }
}

// ---------------------------------------------------------------------------
// Flash attention, S^T form, BARRIER-FREE: K and V^T fragments are 16B
// contiguous in global memory, so they load straight to VGPRs (L1 serves the
// 4x wave duplication, L2 the 8x qt-sibling reuse on the same XCD). LDS holds
// only the per-wave P round-trip (9 KB). Software pipeline: V loads issue at
// iter start (covered by S-MFMA+softmax), next-iter K prefetched into regs.
// ---------------------------------------------------------------------------
__global__ __launch_bounds__(256, 3) void attn(
    const ushort* __restrict__ q, const ushort* __restrict__ k,
    const ushort* __restrict__ vt, const float* __restrict__ mask,
    const int* __restrict__ flags, ushort* __restrict__ y) {
    __shared__ ushort Ps[4][16 * 72];
    const int tid = threadIdx.x;
    const int lane = tid & 63, w = tid >> 6;
    const int l15 = lane & 15, quad = lane >> 4;
    const int bh = blockIdx.x, qt = blockIdx.y;   // bh fastest => qt-siblings same XCD
    const int b2 = bh >> 3, h = bh & 7;
    const int qrow0 = qt * 64 + w * 16;

    s16x8 qf0, qf1;
    {
        const ushort* qp = q + ((size_t)(b2 * 512 + qrow0 + l15)) * 512 + h * 64 + quad * 8;
        qf0 = *(const s16x8*)qp;
        qf1 = *(const s16x8*)(qp + 32);
    }
    f32x4 zero = {0.f, 0.f, 0.f, 0.f};
    f32x4 o[4];
#pragma unroll
    for (int nt = 0; nt < 4; nt++) o[nt] = zero;
    float l_i = 0.f;

    // K A-frag base: key rows, dh chunk quad*8 (+32 for second half)
    const ushort* kbase = k + ((size_t)(b2 * 512 + l15)) * 512 + h * 64 + quad * 8;
    // V^T B-frag base: dh rows, key chunk quad*8 (+32)
    const ushort* vbase = vt + ((size_t)(bh * 64 + l15)) * 512 + quad * 8;
    ushort* Pw = &Ps[w][0];
    const int fl_base = (b2 * 8 + qt) * 8;

    s16x8 kc[8];
#pragma unroll
    for (int mt = 0; mt < 4; mt++) {
        const ushort* p = kbase + (size_t)(mt * 16) * 512;
        kc[2 * mt] = *(const s16x8*)p;
        kc[2 * mt + 1] = *(const s16x8*)(p + 32);
    }

    for (int kt = 0; kt < 8; kt++) {
        // V frags for this tile (latency covered by S-MFMA + softmax below)
        s16x8 vf[8];
#pragma unroll
        for (int nt = 0; nt < 4; nt++) {
            const ushort* p = vbase + (size_t)(nt * 16) * 512 + kt * 64;
            vf[2 * nt] = *(const s16x8*)p;
            vf[2 * nt + 1] = *(const s16x8*)(p + 32);
        }
        // prefetch next K tile into regs
        s16x8 kn[8];
        if (kt < 7) {
#pragma unroll
            for (int mt = 0; mt < 4; mt++) {
                const ushort* p = kbase + (size_t)((kt + 1) * 64 + mt * 16) * 512;
                kn[2 * mt] = *(const s16x8*)p;
                kn[2 * mt + 1] = *(const s16x8*)(p + 32);
            }
        }

        // S^T tiles: row = key (mt*16 + quad*4 + reg), col = qrow (l15)
        f32x4 st[4];
#pragma unroll
        for (int mt = 0; mt < 4; mt++) {
            st[mt] = MFMA16(kc[2 * mt], qf0, zero);
            st[mt] = MFMA16(kc[2 * mt + 1], qf1, st[mt]);
        }

        if (flags[fl_base + kt]) {        // wave-uniform cold path
            const size_t mb = ((size_t)(b2 * 512 + qt * 64 + w * 16 + l15)) * 512 + kt * 64;
#pragma unroll
            for (int mt = 0; mt < 4; mt++)
#pragma unroll
                for (int reg = 0; reg < 4; reg++)
                    st[mt][reg] += (1.f - mask[mb + mt * 16 + quad * 4 + reg]) * MNEG;
        }

        float psum = 0.f;
#pragma unroll
        for (int mt = 0; mt < 4; mt++) {
            float p0 = fast_exp2(st[mt][0]);
            float p1 = fast_exp2(st[mt][1]);
            float p2 = fast_exp2(st[mt][2]);
            float p3 = fast_exp2(st[mt][3]);
            psum += (p0 + p1) + (p2 + p3);
            uint2 pk;
            pk.x = pack_bf2(p0, p1);
            pk.y = pack_bf2(p2, p3);
            *(uint2*)&Pw[l15 * 72 + mt * 16 + quad * 4] = pk;
        }

        // O += P @ V  (per-wave LDS round-trip; in-order DS pipe)
        s16x8 pf0 = *(const s16x8*)&Pw[l15 * 72 + quad * 8];
        s16x8 pf1 = *(const s16x8*)&Pw[l15 * 72 + 32 + quad * 8];
#pragma unroll
        for (int nt = 0; nt < 4; nt++) {
            o[nt] = MFMA16(pf0, vf[2 * nt], o[nt]);
            o[nt] = MFMA16(pf1, vf[2 * nt + 1], o[nt]);
        }

        psum += __shfl_xor(psum, 16);
        psum += __shfl_xor(psum, 32);
        l_i += psum;

#pragma unroll
        for (int i = 0; i < 8; i++) kc[i] = kn[i];
    }

    const float invl = 1.f / l_i;
    float ir[4];
#pragma unroll
    for (int reg = 0; reg < 4; reg++) ir[reg] = __shfl(invl, quad * 4 + reg);
#pragma unroll
    for (int reg = 0; reg < 4; reg++) {
        const int row = qt * 64 + w * 16 + quad * 4 + reg;
        ushort* yp = y + ((size_t)(b2 * 512 + row)) * 512 + h * 64;
#pragma unroll
        for (int nt = 0; nt < 4; nt++)
            yp[nt * 16 + l15] = f2bf(o[nt][reg] * ir[reg]);
    }
}

// ---------------------------------------------------------------------------
// h = silu( LN(y)*(1+scale) + shift ) -> bf16. One wave per row, bf16 input.
// ---------------------------------------------------------------------------
__global__ __launch_bounds__(256) void film_silu(
    const ushort* __restrict__ y, const float* __restrict__ g,
    const float* __restrict__ b, const float* __restrict__ ss,
    ushort* __restrict__ tb) {
    const int r = blockIdx.x * 4 + (threadIdx.x >> 6);
    const int lane = threadIdx.x & 63;
    const int b2 = r >> 9;
    const int d0 = lane * 8;
    s16x8 raw = *(const s16x8*)&y[(size_t)r * 512 + d0];
    float v[8];
#pragma unroll
    for (int j = 0; j < 8; j++) v[j] = bf2f((ushort)raw[j]);
    float s = 0.f, qq = 0.f;
#pragma unroll
    for (int j = 0; j < 8; j++) { s += v[j]; qq += v[j] * v[j]; }
    s = wave_sum(s); qq = wave_sum(qq);
    const float mean = s * (1.f/512.f);
    const float var = qq * (1.f/512.f) - mean * mean;
    const float rs = rsqrtf(var + 1e-5f);
    const float* scp = ss + (size_t)b2 * 1024;
    s16x8 o;
#pragma unroll
    for (int j = 0; j < 8; j++) {
        int d = d0 + j;
        float ln = (v[j] - mean) * rs * g[d] + b[d];
        float hv = ln * (1.f + scp[d]) + scp[512 + d];
        o[j] = (short)f2bf(hv / (1.f + __expf(-hv)));
    }
    *(s16x8*)&tb[(size_t)r * 512 + d0] = o;
}

// ---------------------------------------------------------------------------
extern "C" void kernel_launch(void* const* d_in, const int* in_sizes, int n_in,
                              void* d_out, int out_size, void* d_ws, size_t ws_size,
                              hipStream_t stream) {
    const float* x1     = (const float*)d_in[0];
    const float* x2     = (const float*)d_in[1];
    const float* emb    = (const float*)d_in[2];
    const float* mask   = (const float*)d_in[3];
    const float* ln_x_g = (const float*)d_in[4];
    const float* ln_x_b = (const float*)d_in[5];
    const float* ln_t_g = (const float*)d_in[6];
    const float* ln_t_b = (const float*)d_in[7];
    const float* Wq     = (const float*)d_in[8];
    const float* bq     = (const float*)d_in[9];
    const float* Wk     = (const float*)d_in[10];
    const float* bk     = (const float*)d_in[11];
    const float* Wv     = (const float*)d_in[12];
    const float* bv     = (const float*)d_in[13];
    const float* Wemb   = (const float*)d_in[14];
    const float* bemb   = (const float*)d_in[15];
    const float* sb_g   = (const float*)d_in[16];
    const float* sb_b   = (const float*)d_in[17];
    const float* Wout   = (const float*)d_in[18];
    const float* bout   = (const float*)d_in[19];
    float* out = (float*)d_out;

    char* ws = (char*)d_ws;
    ushort* xn   = (ushort*)(ws + 0);                  // 16 MiB
    ushort* tn   = (ushort*)(ws + (16u << 20));        // 16 MiB
    ushort* qb   = (ushort*)(ws + (32u << 20));        // 16 MiB
    ushort* kb   = (ushort*)(ws + (48u << 20));        // 16 MiB
    ushort* vtb  = (ushort*)(ws + (64u << 20));        // 16 MiB (V^T: [b,h,dh,t])
    ushort* yb   = (ushort*)(ws + (80u << 20));        // 16 MiB (attn out, bf16)
    ushort* wqkv = (ushort*)(ws + (96u << 20));        // 1.5 MiB (Wq|Wk|Wv rows)
    ushort* wto  = wqkv + 786432;                      // 512 KiB
    float*  ss   = (float*)(ws + (98u << 20));         // 128 KiB
    int*    flg  = (int*)(ws + (98u << 20) + (128u << 10));  // 8 KiB
    ushort* tb   = xn;   // reuse: xn dead after qkv-GEMM

    prep<<<7296, 256, 0, stream>>>(Wq, Wk, Wv, Wout,
                                   wqkv, wqkv + 262144, wqkv + 524288, wto,
                                   x1, x2, ln_x_g, ln_x_b, ln_t_g, ln_t_b, xn, tn,
                                   mask, flg, bemb, ss);

    emb_gemm<<<dim3(8, 16), 256, 0, stream>>>(emb, Wemb, ss);

    gemm_qkv<<<1536, 256, 0, stream>>>(xn, tn, wqkv, bq, bk, bv, qb, kb, vtb);

    attn<<<dim3(256, 8), 256, 0, stream>>>(qb, kb, vtb, mask, flg, yb);

    film_silu<<<4096, 256, 0, stream>>>(yb, sb_g, sb_b, ss, tb);

    gemm_out<<<512, 256, 0, stream>>>(tb, wto, bout, out, x1, x2);

    (void)in_sizes; (void)n_in; (void)out_size; (void)ws_size;
}

// Round 7
// 289.880 us; speedup vs baseline: 1.2868x; 1.2868x over previous
//
#include <hip/hip_runtime.h>
#include <hip/hip_bf16.h>
#include <stdint.h>

// B=16, T=512, D=512, H=8, DH=64, TE=2048, B2=32. M = 16384 rows.

typedef float f32x4 __attribute__((ext_vector_type(4)));
typedef short s16x8 __attribute__((ext_vector_type(8)));   // 8 bf16 in 4 VGPRs

#define MFMA16(a, b, c) __builtin_amdgcn_mfma_f32_16x16x32_bf16((a), (b), (c), 0, 0, 0)
// async global->LDS, 16B/lane; LDS dest = wave-uniform base + lane*16
#define GLD16(g, l) __builtin_amdgcn_global_load_lds( \
    (const __attribute__((address_space(1))) void*)(g), \
    (__attribute__((address_space(3))) void*)(l), 16, 0, 0)

__device__ __forceinline__ ushort f2bf(float f) {
    union { float f; uint32_t u; } cv; cv.f = f;
    uint32_t u = cv.u;
    return (ushort)((u + 0x7fffu + ((u >> 16) & 1u)) >> 16);
}
__device__ __forceinline__ float bf2f(ushort u) {
    union { uint32_t u; float f; } cv; cv.u = ((uint32_t)u) << 16;
    return cv.f;
}
// pack two fp32 -> two bf16 (round-to-nearest, carry-correct), 5 VALU ops
__device__ __forceinline__ uint32_t pack_bf2(float a, float b) {
    union { float f; uint32_t u; } x, y; x.f = a; y.f = b;
    return ((x.u + 0x8000u) >> 16) | ((y.u + 0x8000u) & 0xffff0000u);
}
__device__ __forceinline__ float fast_exp2(float x) {
#if __has_builtin(__builtin_amdgcn_exp2f)
    return __builtin_amdgcn_exp2f(x);
#else
    return exp2f(x);
#endif
}
__device__ __forceinline__ float wave_sum(float v) {
#pragma unroll
    for (int o = 32; o > 0; o >>= 1) v += __shfl_xor(v, o);
    return v;
}

#define QSCALE 0.180336880f   // 0.125 * log2(e): folded into q so p = exp2(S)
#define MNEG  -144269.504f    // -1e5 * log2(e): mask penalty in exp2 domain

// ---------------------------------------------------------------------------
// Fused prep kernel — independent work packed into one launch (256-thr blocks):
//  [0,1024)      wconv: Wt[n][k] = bf16(W[k][n]) for Wq/Wk/Wv/Wout
//  [1024,5120)   ln_prep: dual LayerNorm -> xn, tn (4 rows/block)
//  [5120,7168)   maskchk: flags[tile] = any(mask != 1) per 64x64 tile
//  [7168,7296)   ss init: ss[b][n] = bemb[n]
// ---------------------------------------------------------------------------
__global__ __launch_bounds__(256) void prep(
    const float* __restrict__ w0, const float* __restrict__ w1,
    const float* __restrict__ w2, const float* __restrict__ w3,
    ushort* __restrict__ o0, ushort* __restrict__ o1,
    ushort* __restrict__ o2, ushort* __restrict__ o3,
    const float* __restrict__ x1, const float* __restrict__ x2,
    const float* __restrict__ gx, const float* __restrict__ bx,
    const float* __restrict__ gt, const float* __restrict__ bt,
    ushort* __restrict__ xn, ushort* __restrict__ tn,
    const float* __restrict__ mask, int* __restrict__ flags,
    const float* __restrict__ bemb, float* __restrict__ ss) {
    __shared__ float tile[32][33];
    __shared__ int bad4[4];
    const int bid = blockIdx.x, tid = threadIdx.x;

    if (bid < 1024) {
        // ---- weight transpose + cast (32x32 tiles) ----
        const int z = bid >> 8, xy = bid & 255;
        const float* src; ushort* dst;
        switch (z) {
            case 0: src = w0; dst = o0; break;
            case 1: src = w1; dst = o1; break;
            case 2: src = w2; dst = o2; break;
            default: src = w3; dst = o3; break;
        }
        const int n0 = (xy & 15) * 32, k0 = (xy >> 4) * 32;
        const int x = tid & 31, y0 = tid >> 5;
#pragma unroll
        for (int i = 0; i < 4; i++) {
            int yy = y0 + 8 * i;
            tile[yy][x] = src[(size_t)(k0 + yy) * 512 + n0 + x];
        }
        __syncthreads();
#pragma unroll
        for (int i = 0; i < 4; i++) {
            int yy = y0 + 8 * i;
            dst[(size_t)(n0 + yy) * 512 + k0 + x] = f2bf(tile[x][yy]);
        }
    } else if (bid < 5120) {
        // ---- dual LayerNorm, stats once per source row ----
        const int r = (bid - 1024) * 4 + (tid >> 6);
        const int lane = tid & 63;
        const float* src = (r < 8192) ? x1 + (size_t)r * 512
                                      : x2 + (size_t)(r - 8192) * 512;
        const int tr = (r < 8192) ? r + 8192 : r - 8192;
        const int d0 = lane * 4;
        float4 a0 = *(const float4*)&src[d0];
        float4 a1 = *(const float4*)&src[d0 + 256];
        float s = a0.x + a0.y + a0.z + a0.w + a1.x + a1.y + a1.z + a1.w;
        float q = a0.x*a0.x + a0.y*a0.y + a0.z*a0.z + a0.w*a0.w
                + a1.x*a1.x + a1.y*a1.y + a1.z*a1.z + a1.w*a1.w;
        s = wave_sum(s); q = wave_sum(q);
        const float mean = s * (1.f/512.f);
        const float var = q * (1.f/512.f) - mean * mean;
        const float rs = rsqrtf(var + 1e-5f);
        float vals[8] = {a0.x, a0.y, a0.z, a0.w, a1.x, a1.y, a1.z, a1.w};
        ushort* px = xn + (size_t)r * 512;
        ushort* pt = tn + (size_t)tr * 512;
#pragma unroll
        for (int half = 0; half < 2; half++) {
            ushort4 ox, ot;
            ushort* pox = (ushort*)&ox; ushort* pot = (ushort*)&ot;
#pragma unroll
            for (int j = 0; j < 4; j++) {
                int d = d0 + half * 256 + j;
                float nv = (vals[half * 4 + j] - mean) * rs;
                pox[j] = f2bf(nv * gx[d] + bx[d]);
                pot[j] = f2bf(nv * gt[d] + bt[d]);
            }
            *(ushort4*)&px[d0 + half * 256] = ox;
            *(ushort4*)&pt[d0 + half * 256] = ot;
        }
    } else if (bid < 7168) {
        // ---- mask precheck: one block per 64x64 tile, mask read once ----
        const int b = bid - 5120;             // 0..2047
        const int b2 = b >> 6, qt = (b >> 3) & 7, kt = b & 7;
        const int r = tid >> 2, c4 = tid & 3;
        const float* mrow = mask + ((size_t)(b2 * 512 + qt * 64 + r)) * 512 + kt * 64;
        bool bad = false;
#pragma unroll
        for (int j = 0; j < 4; j++) {
            float4 v = *(const float4*)&mrow[(c4 + 4 * j) * 4];
            bad |= (v.x != 1.f) | (v.y != 1.f) | (v.z != 1.f) | (v.w != 1.f);
        }
        unsigned long long bl = __ballot(bad);
        const int w = tid >> 6;
        if ((tid & 63) == 0) bad4[w] = (bl != 0ull);
        __syncthreads();
        if (tid == 0) flags[b] = bad4[0] | bad4[1] | bad4[2] | bad4[3];
    } else {
        // ---- ss init with bias ----
        int i = (bid - 7168) * 256 + tid;     // 32768 total
        ss[i] = bemb[i & 1023];
    }
}

// ---------------------------------------------------------------------------
// emb path: ss[b][0:1024] += silu(emb[b]) @ Wemb  (k-split, fp32 atomics)
// ---------------------------------------------------------------------------
__global__ __launch_bounds__(256) void emb_gemm(const float* __restrict__ emb,
                                                const float* __restrict__ Wemb,
                                                float* __restrict__ ss) {
    __shared__ float es[32 * 128];
    const int n0 = blockIdx.x * 128, k0 = blockIdx.y * 128;
    const int t = threadIdx.x;
#pragma unroll
    for (int i = 0; i < 16; i++) {
        int idx = t + 256 * i;
        int b = idx >> 7, kk = idx & 127;
        float v = emb[(size_t)b * 2048 + k0 + kk];
        es[idx] = v / (1.f + __expf(-v));
    }
    __syncthreads();
    const int n = n0 + (t & 127);
    const int kh = (t >> 7) * 64;
    float acc[32];
#pragma unroll
    for (int b = 0; b < 32; b++) acc[b] = 0.f;
    for (int kk = kh; kk < kh + 64; kk++) {
        float w = Wemb[(size_t)(k0 + kk) * 1024 + n];
#pragma unroll
        for (int b = 0; b < 32; b++) acc[b] += es[b * 128 + kk] * w;
    }
#pragma unroll
    for (int b = 0; b < 32; b++) atomicAdd(&ss[b * 1024 + n], acc[b]);
}

// ---------------------------------------------------------------------------
// Fused QKV GEMM: [16384 x 1536] = {xn|tn}[M x 512] @ Wqkv[1536 x 512]^T.
// m97 regime: single-buffer 32 KB LDS, 2-barrier K-loop, GLD16 + XOR swizzle.
// ---------------------------------------------------------------------------
__global__ __launch_bounds__(256, 3) void gemm_qkv(
    const ushort* __restrict__ xn, const ushort* __restrict__ tn,
    const ushort* __restrict__ W,
    const float* __restrict__ bq, const float* __restrict__ bk,
    const float* __restrict__ bv,
    ushort* __restrict__ qb, ushort* __restrict__ kb,
    ushort* __restrict__ vtb) {
    __shared__ ushort As[128 * 64];
    __shared__ ushort Bs[128 * 64];
    const int tid = threadIdx.x;
    const int lane = tid & 63, w = tid >> 6;
    const int l15 = lane & 15, quad = lane >> 4;
    const int l8 = lane >> 3, c_src = (lane & 7) ^ l8;
    const int bid = blockIdx.x;
    const int xcd = bid & 7, j = bid >> 3;        // j in [0,192)
    const int mt_l = j / 12, nt = j % 12;
    const int m0 = (xcd * 16 + mt_l) * 128, n0 = nt * 128;
    const ushort* A = (n0 < 512) ? xn : tn;
    const int wm = (w >> 1) * 64, wn = (w & 1) * 64;

    f32x4 zero = {0.f, 0.f, 0.f, 0.f};
    f32x4 acc[4][4];
#pragma unroll
    for (int i = 0; i < 4; i++)
#pragma unroll
        for (int jj = 0; jj < 4; jj++) acc[i][jj] = zero;

    const ushort* ga0 = A + (size_t)(m0 + w * 32 + l8) * 512 + c_src * 8;
    const ushort* gb0 = W + (size_t)(n0 + w * 32 + l8) * 512 + c_src * 8;

    for (int k0 = 0; k0 < 512; k0 += 64) {
#pragma unroll
        for (int i = 0; i < 4; i++) {
            GLD16(ga0 + (size_t)(i * 8) * 512 + k0, &As[(w * 32 + i * 8) * 64]);
            GLD16(gb0 + (size_t)(i * 8) * 512 + k0, &Bs[(w * 32 + i * 8) * 64]);
        }
        __syncthreads();
#pragma unroll
        for (int ks = 0; ks < 2; ks++) {
            const int sl = ((ks * 4 + quad) ^ (l15 & 7)) * 8;
            s16x8 af[4], bf[4];
#pragma unroll
            for (int i = 0; i < 4; i++)
                af[i] = *(const s16x8*)&As[(wm + i * 16 + l15) * 64 + sl];
#pragma unroll
            for (int jj = 0; jj < 4; jj++)
                bf[jj] = *(const s16x8*)&Bs[(wn + jj * 16 + l15) * 64 + sl];
#pragma unroll
            for (int i = 0; i < 4; i++)
#pragma unroll
                for (int jj = 0; jj < 4; jj++)
                    acc[i][jj] = MFMA16(af[i], bf[jj], acc[i][jj]);
        }
        __syncthreads();
    }

#pragma unroll
    for (int i = 0; i < 4; i++)
#pragma unroll
        for (int jj = 0; jj < 4; jj++) {
            const int col = n0 + wn + jj * 16 + l15;
            if (n0 < 512) {          // q: bf16, scaled
                const float bvv = bq[col];
#pragma unroll
                for (int reg = 0; reg < 4; reg++) {
                    const int row = m0 + wm + i * 16 + quad * 4 + reg;
                    qb[(size_t)row * 512 + col] = f2bf((acc[i][jj][reg] + bvv) * QSCALE);
                }
            } else if (n0 < 1024) {  // k: bf16 row-major
                const int ck = col - 512;
                const float bvv = bk[ck];
#pragma unroll
                for (int reg = 0; reg < 4; reg++) {
                    const int row = m0 + wm + i * 16 + quad * 4 + reg;
                    kb[(size_t)row * 512 + ck] = f2bf(acc[i][jj][reg] + bvv);
                }
            } else {                 // v: transposed vt[b,h,dh,t]
                const int c2 = col - 1024;
                const float bvv = bv[c2];
                const int b2 = m0 >> 9;
                const int t0 = (m0 & 511) + wm + i * 16 + quad * 4;
                ushort4 o4; ushort* po = (ushort*)&o4;
#pragma unroll
                for (int reg = 0; reg < 4; reg++)
                    po[reg] = f2bf(acc[i][jj][reg] + bvv);
                *(ushort4*)&vtb[((size_t)((b2 * 8 + (c2 >> 6)) * 64 + (c2 & 63))) * 512 + t0] = o4;
            }
        }
}

// ---------------------------------------------------------------------------
// Output GEMM + bias + residual (fp32 out), same m97 regime.
// ---------------------------------------------------------------------------
__global__ __launch_bounds__(256, 3) void gemm_out(
    const ushort* __restrict__ A, const ushort* __restrict__ Bt,
    const float* __restrict__ bias, float* __restrict__ of,
    const float* __restrict__ r1, const float* __restrict__ r2) {
    __shared__ ushort As[128 * 64];
    __shared__ ushort Bs[128 * 64];
    const int tid = threadIdx.x;
    const int lane = tid & 63, w = tid >> 6;
    const int l15 = lane & 15, quad = lane >> 4;
    const int l8 = lane >> 3, c_src = (lane & 7) ^ l8;
    const int bid = blockIdx.x;
    const int xcd = bid & 7, j2 = bid >> 3;       // j2 in [0,64)
    const int m0 = (xcd * 16 + (j2 >> 2)) * 128;
    const int n0 = (j2 & 3) * 128;
    const int wm = (w >> 1) * 64, wn = (w & 1) * 64;

    f32x4 zero = {0.f, 0.f, 0.f, 0.f};
    f32x4 acc[4][4];
#pragma unroll
    for (int i = 0; i < 4; i++)
#pragma unroll
        for (int jj = 0; jj < 4; jj++) acc[i][jj] = zero;

    const ushort* ga0 = A + (size_t)(m0 + w * 32 + l8) * 512 + c_src * 8;
    const ushort* gb0 = Bt + (size_t)(n0 + w * 32 + l8) * 512 + c_src * 8;

    for (int k0 = 0; k0 < 512; k0 += 64) {
#pragma unroll
        for (int i = 0; i < 4; i++) {
            GLD16(ga0 + (size_t)(i * 8) * 512 + k0, &As[(w * 32 + i * 8) * 64]);
            GLD16(gb0 + (size_t)(i * 8) * 512 + k0, &Bs[(w * 32 + i * 8) * 64]);
        }
        __syncthreads();
#pragma unroll
        for (int ks = 0; ks < 2; ks++) {
            const int sl = ((ks * 4 + quad) ^ (l15 & 7)) * 8;
            s16x8 af[4], bf[4];
#pragma unroll
            for (int i = 0; i < 4; i++)
                af[i] = *(const s16x8*)&As[(wm + i * 16 + l15) * 64 + sl];
#pragma unroll
            for (int jj = 0; jj < 4; jj++)
                bf[jj] = *(const s16x8*)&Bs[(wn + jj * 16 + l15) * 64 + sl];
#pragma unroll
            for (int i = 0; i < 4; i++)
#pragma unroll
                for (int jj = 0; jj < 4; jj++)
                    acc[i][jj] = MFMA16(af[i], bf[jj], acc[i][jj]);
        }
        __syncthreads();
    }

#pragma unroll
    for (int i = 0; i < 4; i++)
#pragma unroll
        for (int jj = 0; jj < 4; jj++) {
            const int col = n0 + wn + jj * 16 + l15;
            const float bvv = bias[col];
#pragma unroll
            for (int reg = 0; reg < 4; reg++) {
                const int row = m0 + wm + i * 16 + quad * 4 + reg;
                float res = (row < 8192)
                                ? r1[(size_t)row * 512 + col]
                                : r2[(size_t)(row - 8192) * 512 + col];
                of[(size_t)row * 512 + col] = acc[i][jj][reg] + bvv + res;
            }
        }
}

// ---------------------------------------------------------------------------
// Flash attention, S^T form (R5 structure) widened to 32 q-rows/wave: each
// wave's K/V tile reads from LDS now feed 2x the MFMAs (DS per q-row ~halved).
// Block = 128 q-rows, 4 waves; dbuf K/V staging via GLD16; no online max
// (scale+log2e folded into q; masked keys -> exp2(~-1.4e5) = 0).
// ---------------------------------------------------------------------------
__global__ __launch_bounds__(256, 3) void attn(
    const ushort* __restrict__ q, const ushort* __restrict__ k,
    const ushort* __restrict__ vt, const float* __restrict__ mask,
    const int* __restrict__ flags, ushort* __restrict__ y) {
    __shared__ ushort Ks[2][64 * 64];
    __shared__ ushort Vs[2][64 * 64];
    __shared__ ushort Ps[4][32 * 72];
    const int tid = threadIdx.x;
    const int lane = tid & 63, w = tid >> 6;
    const int l15 = lane & 15, quad = lane >> 4;
    const int l8 = lane >> 3, c_src = (lane & 7) ^ l8;
    const int bh = blockIdx.x, qt = blockIdx.y;   // qt in 0..3 (128 q-rows)
    const int b2 = bh >> 3, h = bh & 7;
    const int qrow0 = qt * 128 + w * 32;

    s16x8 qf[2][2];
#pragma unroll
    for (int qi = 0; qi < 2; qi++) {
        const ushort* qp = q + ((size_t)(b2 * 512 + qrow0 + qi * 16 + l15)) * 512 + h * 64 + quad * 8;
        qf[qi][0] = *(const s16x8*)qp;
        qf[qi][1] = *(const s16x8*)(qp + 32);
    }
    f32x4 zero = {0.f, 0.f, 0.f, 0.f};
    f32x4 o[2][4];
#pragma unroll
    for (int qi = 0; qi < 2; qi++)
#pragma unroll
        for (int nt = 0; nt < 4; nt++) o[qi][nt] = zero;
    float l_i[2] = {0.f, 0.f};

    const ushort* kg0 = k + ((size_t)(b2 * 512 + w * 16 + l8)) * 512 + h * 64 + c_src * 8;
    const ushort* vg0 = vt + ((size_t)(bh * 64 + w * 16 + l8)) * 512 + c_src * 8;
    ushort* Pw = &Ps[w][0];
    const int slq = (quad ^ (l15 & 7)) * 8;
    const int slq4 = ((4 + quad) ^ (l15 & 7)) * 8;
    // flags are per 64-q-row x 64-key tile; wave w covers q-64-tile qt*2+(w>>1)
    const int fl_base = (b2 * 8 + qt * 2 + (w >> 1)) * 8;

    auto stage = [&](int buf, int kt) {
        GLD16(kg0 + (size_t)(kt * 64) * 512, &Ks[buf][(w * 16) * 64]);
        GLD16(kg0 + (size_t)(kt * 64 + 8) * 512, &Ks[buf][(w * 16 + 8) * 64]);
        GLD16(vg0 + kt * 64, &Vs[buf][(w * 16) * 64]);
        GLD16(vg0 + (size_t)8 * 512 + kt * 64, &Vs[buf][(w * 16 + 8) * 64]);
    };
    stage(0, 0);

    for (int kt = 0; kt < 8; kt++) {
        __syncthreads();                  // vmcnt drain => buf[kt&1] staged
        if (kt < 7) stage((kt + 1) & 1, kt + 1);   // overlaps compute below
        const ushort* Kb = Ks[kt & 1];
        const ushort* Vb = Vs[kt & 1];

        // S^T tiles: row = key (mt*16 + quad*4 + reg), col = qrow (l15);
        // K frags read once, used for both q-subtiles.
        f32x4 st[2][4];
#pragma unroll
        for (int mt = 0; mt < 4; mt++) {
            const int row = (mt * 16 + l15) * 64;
            s16x8 kf0 = *(const s16x8*)&Kb[row + slq];
            s16x8 kf1 = *(const s16x8*)&Kb[row + slq4];
            st[0][mt] = MFMA16(kf0, qf[0][0], zero);
            st[0][mt] = MFMA16(kf1, qf[0][1], st[0][mt]);
            st[1][mt] = MFMA16(kf0, qf[1][0], zero);
            st[1][mt] = MFMA16(kf1, qf[1][1], st[1][mt]);
        }

        if (flags[fl_base + kt]) {        // wave-uniform cold path
#pragma unroll
            for (int qi = 0; qi < 2; qi++) {
                const size_t mb = ((size_t)(b2 * 512 + qt * 128 + w * 32 + qi * 16 + l15)) * 512 + kt * 64;
#pragma unroll
                for (int mt = 0; mt < 4; mt++)
#pragma unroll
                    for (int reg = 0; reg < 4; reg++)
                        st[qi][mt][reg] += (1.f - mask[mb + mt * 16 + quad * 4 + reg]) * MNEG;
            }
        }

#pragma unroll
        for (int qi = 0; qi < 2; qi++) {
            float psum = 0.f;
#pragma unroll
            for (int mt = 0; mt < 4; mt++) {
                float p0 = fast_exp2(st[qi][mt][0]);
                float p1 = fast_exp2(st[qi][mt][1]);
                float p2 = fast_exp2(st[qi][mt][2]);
                float p3 = fast_exp2(st[qi][mt][3]);
                psum += (p0 + p1) + (p2 + p3);
                uint2 pk;
                pk.x = pack_bf2(p0, p1);
                pk.y = pack_bf2(p2, p3);
                *(uint2*)&Pw[(qi * 16 + l15) * 72 + mt * 16 + quad * 4] = pk;
            }
            psum += __shfl_xor(psum, 16);
            psum += __shfl_xor(psum, 32);
            l_i[qi] += psum;
        }

        // O += P @ V  (per-wave LDS round-trip; V frags shared across qi)
        s16x8 pf[2][2];
#pragma unroll
        for (int qi = 0; qi < 2; qi++) {
            pf[qi][0] = *(const s16x8*)&Pw[(qi * 16 + l15) * 72 + quad * 8];
            pf[qi][1] = *(const s16x8*)&Pw[(qi * 16 + l15) * 72 + 32 + quad * 8];
        }
#pragma unroll
        for (int nt = 0; nt < 4; nt++) {
            const int vr = (nt * 16 + l15) * 64;
            s16x8 vf0 = *(const s16x8*)&Vb[vr + slq];
            s16x8 vf1 = *(const s16x8*)&Vb[vr + slq4];
            o[0][nt] = MFMA16(pf[0][0], vf0, o[0][nt]);
            o[0][nt] = MFMA16(pf[0][1], vf1, o[0][nt]);
            o[1][nt] = MFMA16(pf[1][0], vf0, o[1][nt]);
            o[1][nt] = MFMA16(pf[1][1], vf1, o[1][nt]);
        }
    }

#pragma unroll
    for (int qi = 0; qi < 2; qi++) {
        const float invl = 1.f / l_i[qi];
        float ir[4];
#pragma unroll
        for (int reg = 0; reg < 4; reg++) ir[reg] = __shfl(invl, quad * 4 + reg);
#pragma unroll
        for (int reg = 0; reg < 4; reg++) {
            const int row = qt * 128 + w * 32 + qi * 16 + quad * 4 + reg;
            ushort* yp = y + ((size_t)(b2 * 512 + row)) * 512 + h * 64;
#pragma unroll
            for (int nt = 0; nt < 4; nt++)
                yp[nt * 16 + l15] = f2bf(o[qi][nt][reg] * ir[reg]);
        }
    }
}

// ---------------------------------------------------------------------------
// h = silu( LN(y)*(1+scale) + shift ) -> bf16. One wave per row, bf16 input.
// ---------------------------------------------------------------------------
__global__ __launch_bounds__(256) void film_silu(
    const ushort* __restrict__ y, const float* __restrict__ g,
    const float* __restrict__ b, const float* __restrict__ ss,
    ushort* __restrict__ tb) {
    const int r = blockIdx.x * 4 + (threadIdx.x >> 6);
    const int lane = threadIdx.x & 63;
    const int b2 = r >> 9;
    const int d0 = lane * 8;
    s16x8 raw = *(const s16x8*)&y[(size_t)r * 512 + d0];
    float v[8];
#pragma unroll
    for (int j = 0; j < 8; j++) v[j] = bf2f((ushort)raw[j]);
    float s = 0.f, qq = 0.f;
#pragma unroll
    for (int j = 0; j < 8; j++) { s += v[j]; qq += v[j] * v[j]; }
    s = wave_sum(s); qq = wave_sum(qq);
    const float mean = s * (1.f/512.f);
    const float var = qq * (1.f/512.f) - mean * mean;
    const float rs = rsqrtf(var + 1e-5f);
    const float* scp = ss + (size_t)b2 * 1024;
    s16x8 o;
#pragma unroll
    for (int j = 0; j < 8; j++) {
        int d = d0 + j;
        float ln = (v[j] - mean) * rs * g[d] + b[d];
        float hv = ln * (1.f + scp[d]) + scp[512 + d];
        o[j] = (short)f2bf(hv / (1.f + __expf(-hv)));
    }
    *(s16x8*)&tb[(size_t)r * 512 + d0] = o;
}

// ---------------------------------------------------------------------------
extern "C" void kernel_launch(void* const* d_in, const int* in_sizes, int n_in,
                              void* d_out, int out_size, void* d_ws, size_t ws_size,
                              hipStream_t stream) {
    const float* x1     = (const float*)d_in[0];
    const float* x2     = (const float*)d_in[1];
    const float* emb    = (const float*)d_in[2];
    const float* mask   = (const float*)d_in[3];
    const float* ln_x_g = (const float*)d_in[4];
    const float* ln_x_b = (const float*)d_in[5];
    const float* ln_t_g = (const float*)d_in[6];
    const float* ln_t_b = (const float*)d_in[7];
    const float* Wq     = (const float*)d_in[8];
    const float* bq     = (const float*)d_in[9];
    const float* Wk     = (const float*)d_in[10];
    const float* bk     = (const float*)d_in[11];
    const float* Wv     = (const float*)d_in[12];
    const float* bv     = (const float*)d_in[13];
    const float* Wemb   = (const float*)d_in[14];
    const float* bemb   = (const float*)d_in[15];
    const float* sb_g   = (const float*)d_in[16];
    const float* sb_b   = (const float*)d_in[17];
    const float* Wout   = (const float*)d_in[18];
    const float* bout   = (const float*)d_in[19];
    float* out = (float*)d_out;

    char* ws = (char*)d_ws;
    ushort* xn   = (ushort*)(ws + 0);                  // 16 MiB
    ushort* tn   = (ushort*)(ws + (16u << 20));        // 16 MiB
    ushort* qb   = (ushort*)(ws + (32u << 20));        // 16 MiB
    ushort* kb   = (ushort*)(ws + (48u << 20));        // 16 MiB
    ushort* vtb  = (ushort*)(ws + (64u << 20));        // 16 MiB (V^T: [b,h,dh,t])
    ushort* yb   = (ushort*)(ws + (80u << 20));        // 16 MiB (attn out, bf16)
    ushort* wqkv = (ushort*)(ws + (96u << 20));        // 1.5 MiB (Wq|Wk|Wv rows)
    ushort* wto  = wqkv + 786432;                      // 512 KiB
    float*  ss   = (float*)(ws + (98u << 20));         // 128 KiB
    int*    flg  = (int*)(ws + (98u << 20) + (128u << 10));  // 8 KiB
    ushort* tb   = xn;   // reuse: xn dead after qkv-GEMM

    prep<<<7296, 256, 0, stream>>>(Wq, Wk, Wv, Wout,
                                   wqkv, wqkv + 262144, wqkv + 524288, wto,
                                   x1, x2, ln_x_g, ln_x_b, ln_t_g, ln_t_b, xn, tn,
                                   mask, flg, bemb, ss);

    emb_gemm<<<dim3(8, 16), 256, 0, stream>>>(emb, Wemb, ss);

    gemm_qkv<<<1536, 256, 0, stream>>>(xn, tn, wqkv, bq, bk, bv, qb, kb, vtb);

    attn<<<dim3(256, 4), 256, 0, stream>>>(qb, kb, vtb, mask, flg, yb);

    film_silu<<<4096, 256, 0, stream>>>(yb, sb_g, sb_b, ss, tb);

    gemm_out<<<512, 256, 0, stream>>>(tb, wto, bout, out, x1, x2);

    (void)in_sizes; (void)n_in; (void)out_size; (void)ws_size;
}